// Round 14
// baseline (357.982 us; speedup 1.0000x reference)
//
#include <hip/hip_runtime.h>
#include <hip/hip_bf16.h>
#include <hip/hip_fp16.h>

#define BB 8
#define NN 1024
#define DD 256
#define RR 12
#define BN (BB * NN)  // 8192
#define ICH 8
#define CCH (NN / ICH)  // 128

typedef __attribute__((ext_vector_type(8))) short short8v;
typedef __attribute__((ext_vector_type(4))) float f32x4;
typedef __attribute__((ext_vector_type(4))) int int4v;
typedef __attribute__((ext_vector_type(2))) uint uint2v;

static __device__ __forceinline__ ushort f2bf(float f) {
  union { float f; uint u; } v; v.f = f;
  uint r = v.u + 0x7FFF + ((v.u >> 16) & 1);
  return (ushort)(r >> 16);
}
static __device__ __forceinline__ uint pack2(float a, float b) {
  return (uint)f2bf(a) | ((uint)f2bf(b) << 16);
}
static __device__ __forceinline__ float bfround(float f) {
  union { uint u; float f; } v; v.u = (uint)f2bf(f) << 16;
  return v.f;
}

// ---- K0: bitpack masks. slab 0 = adj, slabs 1..12 = madj. ----
// Each block: 128KB contiguous of ONE slab; thread-private word packing.
__global__ __launch_bounds__(256) void k_pack(const int* __restrict__ madj,
                                              const int* __restrict__ adj,
                                              uint* __restrict__ packed) {
  int blk = blockIdx.x;            // 0..3327
  int s = blk >> 8;                // 0..12
  int c = blk & 255;               // 0..255
  const int* src = (s == 0) ? adj : madj + (long)(s - 1) * BB * NN * NN;
  int tid = threadIdx.x;
  int w = tid & 31;                // word within row (j = w*32..w*32+31)
  int rsub = tid >> 5;             // 0..7
#pragma unroll
  for (int pass = 0; pass < 4; ++pass) {
    long row = (long)c * 32 + pass * 8 + rsub;   // 0..8191 (b*NN+i)
    const int* rp = src + row * NN + w * 32;
    uint bits = 0;
#pragma unroll
    for (int q = 0; q < 8; ++q) {
      int4v mv = __builtin_nontemporal_load((const int4v*)(rp + q * 4));
      bits |= (mv.x > 0 ? 1u : 0u) << (q * 4);
      bits |= (mv.y > 0 ? 2u : 0u) << (q * 4);
      bits |= (mv.z > 0 ? 4u : 0u) << (q * 4);
      bits |= (mv.w > 0 ? 8u : 0u) << (q * 4);
    }
    packed[((long)s * BN + row) * 32 + w] = bits;
  }
}

// ---- K1: prepW transpose (blk 0..15) + Vt (16..223) + zero lsum (224) ----
__global__ __launch_bounds__(256) void k_prep(const float* __restrict__ W,
                                              const float* __restrict__ a,
                                              const float* __restrict__ A_rel,
                                              ushort* __restrict__ WTb,
                                              float* __restrict__ Vt,
                                              float* __restrict__ lsum) {
  __shared__ float Ls[64][65];
  int blk = blockIdx.x, tid = threadIdx.x;
  if (blk < 16) {
    int k0 = (blk & 3) * 64, d0 = (blk >> 2) * 64;
    int rr = tid >> 4, c = (tid & 15) * 4;
#pragma unroll
    for (int p = 0; p < 4; ++p) {
      int row = p * 16 + rr;
      float4 v = *(const float4*)&W[(k0 + row) * DD + d0 + c];
      Ls[row][c] = v.x; Ls[row][c + 1] = v.y; Ls[row][c + 2] = v.z; Ls[row][c + 3] = v.w;
    }
    __syncthreads();
    int r2 = tid >> 3, cc = (tid & 7) * 8;
#pragma unroll
    for (int p = 0; p < 2; ++p) {
      int d = p * 32 + r2;
      uint4 q;
      q.x = pack2(Ls[cc + 0][d], Ls[cc + 1][d]);
      q.y = pack2(Ls[cc + 2][d], Ls[cc + 3][d]);
      q.z = pack2(Ls[cc + 4][d], Ls[cc + 5][d]);
      q.w = pack2(Ls[cc + 6][d], Ls[cc + 7][d]);
      *(uint4*)&WTb[(d0 + d) * DD + k0 + cc] = q;
    }
  } else if (blk == 224) {
    float4 z = make_float4(0.f, 0.f, 0.f, 0.f);
#pragma unroll
    for (int p = 0; p < 8; ++p)
      *(float4*)&lsum[(p * 256 + tid) * 4] = z;
  } else {
    int idx = blk - 16;            // 0..207
    int combo = idx >> 3;          // 0..25
    int sub = idx & 7;             // 0..7
    int half = combo >= 13 ? 1 : 0;
    int c = combo - half * 13;
    int lane = tid & 63, w = tid >> 6;
    const float* X = (c == 0) ? &a[half * DD] : &A_rel[(c - 1) * 2 * DD + half * DD];
    float4 x4 = *(const float4*)&X[lane * 4];
#pragma unroll
    for (int kk = 0; kk < 8; ++kk) {
      int k = sub * 32 + kk * 4 + w;
      float4 w4 = *(const float4*)&W[k * DD + lane * 4];
      float p = w4.x * x4.x + w4.y * x4.y + w4.z * x4.z + w4.w * x4.w;
#pragma unroll
      for (int off = 32; off; off >>= 1) p += __shfl_xor(p, off);
      if (lane == 0) Vt[(half * 13 + c) * DD + k] = p;
    }
  }
}

// ---------------- K2: per-node projections from h and Vt ----------------
__global__ __launch_bounds__(256) void k_proj(const float* __restrict__ h0,
                                              const float* __restrict__ h1,
                                              const float* __restrict__ Vt,
                                              float* __restrict__ s0, float* __restrict__ s1,
                                              float* __restrict__ r0, float* __restrict__ r1) {
  int wid = (blockIdx.x * 256 + threadIdx.x) >> 6;  // 0..16383
  int lane = threadIdx.x & 63;
  int mat = wid >> 13;
  int row = wid & (BN - 1);
  const float* h = mat ? h1 : h0;
  float4 h4 = *(const float4*)&h[(long)row * DD + lane * 4];
  float p[13];
#pragma unroll
  for (int c = 0; c < 13; ++c) {
    float4 v4 = *(const float4*)&Vt[(mat * 13 + c) * DD + lane * 4];
    p[c] = h4.x * v4.x + h4.y * v4.y + h4.z * v4.z + h4.w * v4.w;
  }
#pragma unroll
  for (int off = 32; off; off >>= 1)
#pragma unroll
    for (int c = 0; c < 13; ++c) p[c] += __shfl_xor(p[c], off);
  if (lane == 0) {
    if (mat == 0) {
      s0[row] = p[0];
      for (int c = 1; c < 13; ++c) r0[(c - 1) * BN + row] = p[c];
    } else {
      s1[row] = p[0];
      for (int c = 1; c < 13; ++c) r1[(c - 1) * BN + row] = p[c];
    }
  }
}

// ------ K3: scores from packed bits -> U = bf16(exp(S-4)) + atomic lsum -----
__global__ __launch_bounds__(256) void k_scores(const uint* __restrict__ packed,
                                                const float* __restrict__ s0,
                                                const float* __restrict__ s1,
                                                const float* __restrict__ r0,
                                                const float* __restrict__ r1,
                                                ushort* __restrict__ U,
                                                float* __restrict__ lsum) {
  int b = blockIdx.x, c = blockIdx.y;
  int tid = threadIdx.x;
  int j4 = tid * 4;
  int i0 = c * ICH;
  int woff = tid >> 3;
  int bsh = (tid & 7) * 4;
  __shared__ float s0c[ICH];
  __shared__ float r0c[RR][ICH];
  if (tid < (RR + 1) * ICH) {
    int v = tid / ICH, i = tid % ICH;
    float x = (v == 0) ? s0[b * NN + i0 + i] : r0[(v - 1) * BN + b * NN + i0 + i];
    if (v == 0) s0c[i] = x; else r0c[v - 1][i] = x;
  }
  __syncthreads();
  float4 s14 = *(const float4*)&s1[b * NN + j4];
  float rel[ICH][4] = {};
#pragma unroll
  for (int r = 0; r < RR; ++r) {
    float4 r1v = *(const float4*)&r1[r * BN + b * NN + j4];
#pragma unroll
    for (int i = 0; i < ICH; ++i) {
      uint wb = packed[((long)(r + 1) * BN + b * NN + i0 + i) * 32 + woff] >> bsh;
      float r0v = r0c[r][i];
      float t0 = r0v + r1v.x; t0 = t0 >= 0.f ? t0 : 0.2f * t0;
      float t1 = r0v + r1v.y; t1 = t1 >= 0.f ? t1 : 0.2f * t1;
      float t2 = r0v + r1v.z; t2 = t2 >= 0.f ? t2 : 0.2f * t2;
      float t3 = r0v + r1v.w; t3 = t3 >= 0.f ? t3 : 0.2f * t3;
      if (wb & 1u) rel[i][0] += t0;
      if (wb & 2u) rel[i][1] += t1;
      if (wb & 4u) rel[i][2] += t2;
      if (wb & 8u) rel[i][3] += t3;
    }
  }
  float l0 = 0.f, l1 = 0.f, l2 = 0.f, l3 = 0.f;
#pragma unroll
  for (int i = 0; i < ICH; ++i) {
    uint ab = packed[((long)b * NN + i0 + i) * 32 + woff] >> bsh;
    float s0v = s0c[i];
    float u0, u1, u2, u3;
    { float e = s0v + s14.x; e = e >= 0.f ? e : 0.2f * e;
      u0 = __expf(((ab & 1u) ? e : -9e15f) + 0.01f * rel[i][0] - 4.0f); }
    { float e = s0v + s14.y; e = e >= 0.f ? e : 0.2f * e;
      u1 = __expf(((ab & 2u) ? e : -9e15f) + 0.01f * rel[i][1] - 4.0f); }
    { float e = s0v + s14.z; e = e >= 0.f ? e : 0.2f * e;
      u2 = __expf(((ab & 4u) ? e : -9e15f) + 0.01f * rel[i][2] - 4.0f); }
    { float e = s0v + s14.w; e = e >= 0.f ? e : 0.2f * e;
      u3 = __expf(((ab & 8u) ? e : -9e15f) + 0.01f * rel[i][3] - 4.0f); }
    u0 = bfround(u0); u1 = bfround(u1); u2 = bfround(u2); u3 = bfround(u3);
    uint2v so;
    so.x = pack2(u0, u1);
    so.y = pack2(u2, u3);
    *(uint2v*)&U[((long)b * NN + i0 + i) * NN + j4] = so;
    l0 += u0; l1 += u1; l2 += u2; l3 += u3;
  }
  float* lp = &lsum[b * NN + j4];
  atomicAdd(lp + 0, l0);
  atomicAdd(lp + 1, l1);
  atomicAdd(lp + 2, l2);
  atomicAdd(lp + 3, l3);
}

// ------ K4: WhT[b][d][i] = bf16( (h1@W)[i][d] / lsum[i] ), fused transpose --
__global__ __launch_bounds__(256) void k_mm_wh1(const float* __restrict__ h1,
                                                const ushort* __restrict__ WTb,
                                                const float* __restrict__ lsum,
                                                ushort* __restrict__ WhT) {
  __shared__ __align__(16) char smraw[24576];
  uint4* AswQ = (uint4*)smraw;
  uint4* BswQ = (uint4*)(smraw + 8192);
  typedef ushort LtRow[72];
  LtRow* Lt = (LtRow*)smraw;
  int n0 = blockIdx.x * 128, i0 = blockIdx.y * 64;
  int tid = threadIdx.x;
  int r = tid >> 3, cs = tid & 7;
  int lane = tid & 63, wid = tid >> 6;
  int wm = wid >> 1, wn = wid & 1;
  int lr = lane & 15, g = lane >> 4;
  f32x4 acc[2][4] = {};
  for (int k0 = 0; k0 < DD; k0 += 64) {
#pragma unroll
    for (int p = 0; p < 2; ++p) {
      int row = p * 32 + r;
      const float* src = h1 + (long)(i0 + row) * DD + k0 + cs * 8;
      float4 v0 = *(const float4*)src;
      float4 v1 = *(const float4*)(src + 4);
      uint4 q;
      q.x = pack2(v0.x, v0.y); q.y = pack2(v0.z, v0.w);
      q.z = pack2(v1.x, v1.y); q.w = pack2(v1.z, v1.w);
      AswQ[row * 8 + (cs ^ (row & 7))] = q;
    }
#pragma unroll
    for (int p = 0; p < 4; ++p) {
      int row = p * 32 + r;
      uint4 q = *(const uint4*)(WTb + (long)(n0 + row) * DD + k0 + cs * 8);
      BswQ[row * 8 + (cs ^ (row & 7))] = q;
    }
    __syncthreads();
#pragma unroll
    for (int ks = 0; ks < 2; ++ks) {
      short8v af[2], bfr[4];
      int slot = ks * 4 + g;
#pragma unroll
      for (int mi = 0; mi < 2; ++mi) {
        int row = wm * 32 + mi * 16 + lr;
        af[mi] = *reinterpret_cast<const short8v*>(&AswQ[row * 8 + (slot ^ (row & 7))]);
      }
#pragma unroll
      for (int ni = 0; ni < 4; ++ni) {
        int row = wn * 64 + ni * 16 + lr;
        bfr[ni] = *reinterpret_cast<const short8v*>(&BswQ[row * 8 + (slot ^ (row & 7))]);
      }
#pragma unroll
      for (int mi = 0; mi < 2; ++mi)
#pragma unroll
        for (int ni = 0; ni < 4; ++ni)
          acc[mi][ni] = __builtin_amdgcn_mfma_f32_16x16x32_bf16(af[mi], bfr[ni], acc[mi][ni], 0, 0, 0);
    }
    __syncthreads();
  }
#pragma unroll
  for (int mi = 0; mi < 2; ++mi) {
    int ib = wm * 32 + mi * 16 + g * 4;
    float4 lv = *(const float4*)&lsum[i0 + ib];
    float inv0 = 1.0f / lv.x, inv1 = 1.0f / lv.y, inv2 = 1.0f / lv.z, inv3 = 1.0f / lv.w;
#pragma unroll
    for (int ni = 0; ni < 4; ++ni) {
      int d = wn * 64 + ni * 16 + lr;
      uint2 w;
      w.x = pack2(acc[mi][ni][0] * inv0, acc[mi][ni][1] * inv1);
      w.y = pack2(acc[mi][ni][2] * inv2, acc[mi][ni][3] * inv3);
      *(uint2*)&Lt[d][ib] = w;
    }
  }
  __syncthreads();
  int b = i0 >> 10, il = i0 & 1023;
#pragma unroll
  for (int p = 0; p < 4; ++p) {
    int row = (tid >> 3) + p * 32;
    int ch = (tid & 7) * 8;
    uint4 q = *(uint4*)&Lt[row][ch];
    *(uint4*)&WhT[((long)b * DD + n0 + row) * NN + il + ch] = q;
  }
}

// -------- K5: out = elu( U @ WhT^T ), BM=64 BN=64, register prefetch --------
__global__ __launch_bounds__(256) void k_av(const ushort* __restrict__ U,
                                            const ushort* __restrict__ WhT,
                                            float* __restrict__ out) {
  __shared__ uint4 AswQ[64 * 8];
  __shared__ uint4 BswQ[64 * 8];
  int b = blockIdx.z;
  int i0 = blockIdx.y * 64;
  int n0 = blockIdx.x * 64;
  const ushort* Sb = U + (long)b * NN * NN;
  const ushort* Bb = WhT + (long)b * DD * NN;
  int tid = threadIdx.x;
  int r = tid >> 3, cs = tid & 7;
  int lane = tid & 63, wid = tid >> 6;
  int lr = lane & 15, g = lane >> 4;
  f32x4 acc[4] = {};
  uint4 a_pf[2], b_pf[2];
#pragma unroll
  for (int p = 0; p < 2; ++p) {
    int row = p * 32 + r;
    a_pf[p] = *(const uint4*)(Sb + (long)(i0 + row) * NN + cs * 8);
    b_pf[p] = *(const uint4*)(Bb + (long)(n0 + row) * NN + cs * 8);
  }
  for (int k0 = 0; k0 < NN; k0 += 64) {
#pragma unroll
    for (int p = 0; p < 2; ++p) {
      int row = p * 32 + r;
      AswQ[row * 8 + (cs ^ (row & 7))] = a_pf[p];
      BswQ[row * 8 + (cs ^ (row & 7))] = b_pf[p];
    }
    __syncthreads();
    if (k0 + 64 < NN) {
#pragma unroll
      for (int p = 0; p < 2; ++p) {
        int row = p * 32 + r;
        a_pf[p] = *(const uint4*)(Sb + (long)(i0 + row) * NN + k0 + 64 + cs * 8);
        b_pf[p] = *(const uint4*)(Bb + (long)(n0 + row) * NN + k0 + 64 + cs * 8);
      }
    }
#pragma unroll
    for (int ks = 0; ks < 2; ++ks) {
      short8v af, bfr[4];
      int slot = ks * 4 + g;
      {
        int row = wid * 16 + lr;
        af = *reinterpret_cast<const short8v*>(&AswQ[row * 8 + (slot ^ (row & 7))]);
      }
#pragma unroll
      for (int ni = 0; ni < 4; ++ni) {
        int row = ni * 16 + lr;
        bfr[ni] = *reinterpret_cast<const short8v*>(&BswQ[row * 8 + (slot ^ (row & 7))]);
      }
#pragma unroll
      for (int ni = 0; ni < 4; ++ni)
        acc[ni] = __builtin_amdgcn_mfma_f32_16x16x32_bf16(af, bfr[ni], acc[ni], 0, 0, 0);
    }
    __syncthreads();
  }
#pragma unroll
  for (int ni = 0; ni < 4; ++ni)
#pragma unroll
    for (int q = 0; q < 4; ++q) {
      int row = i0 + wid * 16 + g * 4 + q;
      int col = n0 + ni * 16 + lr;
      float x = acc[ni][q];
      x = x > 0.f ? x : expm1f(x);
      out[((long)b * NN + row) * DD + col] = x;
    }
}

extern "C" void kernel_launch(void* const* d_in, const int* in_sizes, int n_in,
                              void* d_out, int out_size, void* d_ws, size_t ws_size,
                              hipStream_t stream) {
  const float* h0 = (const float*)d_in[0];
  const float* h1 = (const float*)d_in[1];
  const int* madj = (const int*)d_in[2];
  const int* adj = (const int*)d_in[3];
  const float* W = (const float*)d_in[4];
  const float* a = (const float*)d_in[5];
  const float* A_rel = (const float*)d_in[6];
  float* out = (float*)d_out;

  float* ws = (float*)d_ws;
  float* s0 = ws;                           // 8192
  float* s1 = s0 + BN;
  float* r0 = s1 + BN;                      // 98304
  float* r1 = r0 + RR * BN;
  float* lsum = r1 + RR * BN;               // 8192
  float* Vt = lsum + BN;                    // 6656
  ushort* WTb = (ushort*)(Vt + 26 * DD);    // 65,536 ushort
  ushort* WhT = WTb + DD * DD;              // 2,097,152 ushort
  ushort* Uh = WhT + (size_t)BB * DD * NN;  // 8,388,608 ushort (bf16)
  uint* packed = (uint*)(Uh + (size_t)BB * NN * NN);  // 13*8192*32 uint = 13.6 MB

  k_pack<<<13 * 256, 256, 0, stream>>>(madj, adj, packed);
  k_prep<<<225, 256, 0, stream>>>(W, a, A_rel, WTb, Vt, lsum);
  k_proj<<<(2 * BN) / 4, 256, 0, stream>>>(h0, h1, Vt, s0, s1, r0, r1);
  k_scores<<<dim3(BB, CCH), 256, 0, stream>>>(packed, s0, s1, r0, r1, Uh, lsum);
  k_mm_wh1<<<dim3(2, BN / 64), 256, 0, stream>>>(h1, WTb, lsum, WhT);
  k_av<<<dim3(DD / 64, NN / 64, BB), 256, 0, stream>>>(Uh, WhT, out);
}

// Round 15
// 169.665 us; speedup vs baseline: 2.1099x; 2.1099x over previous
//
#include <hip/hip_runtime.h>
#include <hip/hip_bf16.h>
#include <hip/hip_fp16.h>

#define BB 8
#define NN 1024
#define DD 256
#define RR 12
#define BN (BB * NN)  // 8192
#define ICH 8
#define CCH (NN / ICH)  // 128

typedef __attribute__((ext_vector_type(8))) short short8v;
typedef __attribute__((ext_vector_type(4))) float f32x4;
typedef __attribute__((ext_vector_type(4))) int int4v;
typedef __attribute__((ext_vector_type(2))) uint uint2v;

static __device__ __forceinline__ ushort f2bf(float f) {
  union { float f; uint u; } v; v.f = f;
  uint r = v.u + 0x7FFF + ((v.u >> 16) & 1);
  return (ushort)(r >> 16);
}
static __device__ __forceinline__ uint pack2(float a, float b) {
  return (uint)f2bf(a) | ((uint)f2bf(b) << 16);
}
static __device__ __forceinline__ float bfround(float f) {
  union { uint u; float f; } v; v.u = (uint)f2bf(f) << 16;
  return v.f;
}

// ---- K1: prepW transpose (blk 0..15) + Vt (16..223, parallel) + lsum (224) --
__global__ __launch_bounds__(256) void k_prep(const float* __restrict__ W,
                                              const float* __restrict__ a,
                                              const float* __restrict__ A_rel,
                                              ushort* __restrict__ WTb,
                                              float* __restrict__ Vt,
                                              float* __restrict__ lsum) {
  __shared__ float Ls[64][65];
  int blk = blockIdx.x, tid = threadIdx.x;
  if (blk < 16) {
    int k0 = (blk & 3) * 64, d0 = (blk >> 2) * 64;
    int rr = tid >> 4, c = (tid & 15) * 4;
#pragma unroll
    for (int p = 0; p < 4; ++p) {
      int row = p * 16 + rr;
      float4 v = *(const float4*)&W[(k0 + row) * DD + d0 + c];
      Ls[row][c] = v.x; Ls[row][c + 1] = v.y; Ls[row][c + 2] = v.z; Ls[row][c + 3] = v.w;
    }
    __syncthreads();
    int r2 = tid >> 3, cc = (tid & 7) * 8;
#pragma unroll
    for (int p = 0; p < 2; ++p) {
      int d = p * 32 + r2;
      uint4 q;
      q.x = pack2(Ls[cc + 0][d], Ls[cc + 1][d]);
      q.y = pack2(Ls[cc + 2][d], Ls[cc + 3][d]);
      q.z = pack2(Ls[cc + 4][d], Ls[cc + 5][d]);
      q.w = pack2(Ls[cc + 6][d], Ls[cc + 7][d]);
      *(uint4*)&WTb[(d0 + d) * DD + k0 + cc] = q;
    }
  } else if (blk == 224) {
    float4 z = make_float4(0.f, 0.f, 0.f, 0.f);
#pragma unroll
    for (int p = 0; p < 8; ++p)
      *(float4*)&lsum[(p * 256 + tid) * 4] = z;
  } else {
    int idx = blk - 16;            // 0..207
    int combo = idx >> 3;          // 0..25
    int sub = idx & 7;             // 0..7 (32 k's each)
    int half = combo >= 13 ? 1 : 0;
    int c = combo - half * 13;
    int lane = tid & 63, w = tid >> 6;
    const float* X = (c == 0) ? &a[half * DD] : &A_rel[(c - 1) * 2 * DD + half * DD];
    float4 x4 = *(const float4*)&X[lane * 4];
#pragma unroll
    for (int kk = 0; kk < 8; ++kk) {
      int k = sub * 32 + kk * 4 + w;
      float4 w4 = *(const float4*)&W[k * DD + lane * 4];
      float p = w4.x * x4.x + w4.y * x4.y + w4.z * x4.z + w4.w * x4.w;
#pragma unroll
      for (int off = 32; off; off >>= 1) p += __shfl_xor(p, off);
      if (lane == 0) Vt[(half * 13 + c) * DD + k] = p;
    }
  }
}

// ---------------- K2: per-node projections from h and Vt ----------------
__global__ __launch_bounds__(256) void k_proj(const float* __restrict__ h0,
                                              const float* __restrict__ h1,
                                              const float* __restrict__ Vt,
                                              float* __restrict__ s0, float* __restrict__ s1,
                                              float* __restrict__ r0, float* __restrict__ r1) {
  int wid = (blockIdx.x * 256 + threadIdx.x) >> 6;  // 0..16383
  int lane = threadIdx.x & 63;
  int mat = wid >> 13;
  int row = wid & (BN - 1);
  const float* h = mat ? h1 : h0;
  float4 h4 = *(const float4*)&h[(long)row * DD + lane * 4];
  float p[13];
#pragma unroll
  for (int c = 0; c < 13; ++c) {
    float4 v4 = *(const float4*)&Vt[(mat * 13 + c) * DD + lane * 4];
    p[c] = h4.x * v4.x + h4.y * v4.y + h4.z * v4.z + h4.w * v4.w;
  }
#pragma unroll
  for (int off = 32; off; off >>= 1)
#pragma unroll
    for (int c = 0; c < 13; ++c) p[c] += __shfl_xor(p[c], off);
  if (lane == 0) {
    if (mat == 0) {
      s0[row] = p[0];
      for (int c = 1; c < 13; ++c) r0[(c - 1) * BN + row] = p[c];
    } else {
      s1[row] = p[0];
      for (int c = 1; c < 13; ++c) r1[(c - 1) * BN + row] = p[c];
    }
  }
}

// ------ K3: scores (R13 body; r-loop unroll 4) ------------------------------
__global__ __launch_bounds__(256) void k_scores(const int* __restrict__ madj,
                                                const int* __restrict__ adj,
                                                const float* __restrict__ s0,
                                                const float* __restrict__ s1,
                                                const float* __restrict__ r0,
                                                const float* __restrict__ r1,
                                                ushort* __restrict__ U,
                                                float* __restrict__ lsum) {
  int b = blockIdx.x, c = blockIdx.y;
  int tid = threadIdx.x;
  int j4 = tid * 4;
  int i0 = c * ICH;
  __shared__ float s0c[ICH];
  __shared__ float r0c[RR][ICH];
  if (tid < (RR + 1) * ICH) {
    int v = tid / ICH, i = tid % ICH;
    float x = (v == 0) ? s0[b * NN + i0 + i] : r0[(v - 1) * BN + b * NN + i0 + i];
    if (v == 0) s0c[i] = x; else r0c[v - 1][i] = x;
  }
  __syncthreads();
  float4 s14 = *(const float4*)&s1[b * NN + j4];
  float rel[ICH][4] = {};
#pragma unroll 4
  for (int r = 0; r < RR; ++r) {
    float4 r1v = *(const float4*)&r1[r * BN + b * NN + j4];
#pragma unroll
    for (int i = 0; i < ICH; ++i) {
      int4v mv = __builtin_nontemporal_load(
          (const int4v*)&madj[(((long)r * BB + b) * NN + i0 + i) * NN + j4]);
      float r0v = r0c[r][i];
      float t0 = r0v + r1v.x; t0 = t0 >= 0.f ? t0 : 0.2f * t0;
      float t1 = r0v + r1v.y; t1 = t1 >= 0.f ? t1 : 0.2f * t1;
      float t2 = r0v + r1v.z; t2 = t2 >= 0.f ? t2 : 0.2f * t2;
      float t3 = r0v + r1v.w; t3 = t3 >= 0.f ? t3 : 0.2f * t3;
      if (mv.x > 0) rel[i][0] += t0;
      if (mv.y > 0) rel[i][1] += t1;
      if (mv.z > 0) rel[i][2] += t2;
      if (mv.w > 0) rel[i][3] += t3;
    }
  }
  float l0 = 0.f, l1 = 0.f, l2 = 0.f, l3 = 0.f;
#pragma unroll
  for (int i = 0; i < ICH; ++i) {
    int4v av = __builtin_nontemporal_load(
        (const int4v*)&adj[((long)b * NN + i0 + i) * NN + j4]);
    float s0v = s0c[i];
    float u0, u1, u2, u3;
    { float e = s0v + s14.x; e = e >= 0.f ? e : 0.2f * e;
      u0 = __expf((av.x > 0 ? e : -9e15f) + 0.01f * rel[i][0] - 4.0f); }
    { float e = s0v + s14.y; e = e >= 0.f ? e : 0.2f * e;
      u1 = __expf((av.y > 0 ? e : -9e15f) + 0.01f * rel[i][1] - 4.0f); }
    { float e = s0v + s14.z; e = e >= 0.f ? e : 0.2f * e;
      u2 = __expf((av.z > 0 ? e : -9e15f) + 0.01f * rel[i][2] - 4.0f); }
    { float e = s0v + s14.w; e = e >= 0.f ? e : 0.2f * e;
      u3 = __expf((av.w > 0 ? e : -9e15f) + 0.01f * rel[i][3] - 4.0f); }
    u0 = bfround(u0); u1 = bfround(u1); u2 = bfround(u2); u3 = bfround(u3);
    uint2v so;
    so.x = pack2(u0, u1);
    so.y = pack2(u2, u3);
    *(uint2v*)&U[((long)b * NN + i0 + i) * NN + j4] = so;
    l0 += u0; l1 += u1; l2 += u2; l3 += u3;
  }
  float* lp = &lsum[b * NN + j4];
  atomicAdd(lp + 0, l0);
  atomicAdd(lp + 1, l1);
  atomicAdd(lp + 2, l2);
  atomicAdd(lp + 3, l3);
}

// ------ K4: WhT[b][d][i] = bf16( (h1@W)[i][d] / lsum[i] ), fused transpose --
__global__ __launch_bounds__(256) void k_mm_wh1(const float* __restrict__ h1,
                                                const ushort* __restrict__ WTb,
                                                const float* __restrict__ lsum,
                                                ushort* __restrict__ WhT) {
  __shared__ __align__(16) char smraw[24576];
  uint4* AswQ = (uint4*)smraw;
  uint4* BswQ = (uint4*)(smraw + 8192);
  typedef ushort LtRow[72];
  LtRow* Lt = (LtRow*)smraw;
  int n0 = blockIdx.x * 128, i0 = blockIdx.y * 64;
  int tid = threadIdx.x;
  int r = tid >> 3, cs = tid & 7;
  int lane = tid & 63, wid = tid >> 6;
  int wm = wid >> 1, wn = wid & 1;
  int lr = lane & 15, g = lane >> 4;
  f32x4 acc[2][4] = {};
  for (int k0 = 0; k0 < DD; k0 += 64) {
#pragma unroll
    for (int p = 0; p < 2; ++p) {
      int row = p * 32 + r;
      const float* src = h1 + (long)(i0 + row) * DD + k0 + cs * 8;
      float4 v0 = *(const float4*)src;
      float4 v1 = *(const float4*)(src + 4);
      uint4 q;
      q.x = pack2(v0.x, v0.y); q.y = pack2(v0.z, v0.w);
      q.z = pack2(v1.x, v1.y); q.w = pack2(v1.z, v1.w);
      AswQ[row * 8 + (cs ^ (row & 7))] = q;
    }
#pragma unroll
    for (int p = 0; p < 4; ++p) {
      int row = p * 32 + r;
      uint4 q = *(const uint4*)(WTb + (long)(n0 + row) * DD + k0 + cs * 8);
      BswQ[row * 8 + (cs ^ (row & 7))] = q;
    }
    __syncthreads();
#pragma unroll
    for (int ks = 0; ks < 2; ++ks) {
      short8v af[2], bfr[4];
      int slot = ks * 4 + g;
#pragma unroll
      for (int mi = 0; mi < 2; ++mi) {
        int row = wm * 32 + mi * 16 + lr;
        af[mi] = *reinterpret_cast<const short8v*>(&AswQ[row * 8 + (slot ^ (row & 7))]);
      }
#pragma unroll
      for (int ni = 0; ni < 4; ++ni) {
        int row = wn * 64 + ni * 16 + lr;
        bfr[ni] = *reinterpret_cast<const short8v*>(&BswQ[row * 8 + (slot ^ (row & 7))]);
      }
#pragma unroll
      for (int mi = 0; mi < 2; ++mi)
#pragma unroll
        for (int ni = 0; ni < 4; ++ni)
          acc[mi][ni] = __builtin_amdgcn_mfma_f32_16x16x32_bf16(af[mi], bfr[ni], acc[mi][ni], 0, 0, 0);
    }
    __syncthreads();
  }
#pragma unroll
  for (int mi = 0; mi < 2; ++mi) {
    int ib = wm * 32 + mi * 16 + g * 4;
    float4 lv = *(const float4*)&lsum[i0 + ib];
    float inv0 = 1.0f / lv.x, inv1 = 1.0f / lv.y, inv2 = 1.0f / lv.z, inv3 = 1.0f / lv.w;
#pragma unroll
    for (int ni = 0; ni < 4; ++ni) {
      int d = wn * 64 + ni * 16 + lr;
      uint2 w;
      w.x = pack2(acc[mi][ni][0] * inv0, acc[mi][ni][1] * inv1);
      w.y = pack2(acc[mi][ni][2] * inv2, acc[mi][ni][3] * inv3);
      *(uint2*)&Lt[d][ib] = w;
    }
  }
  __syncthreads();
  int b = i0 >> 10, il = i0 & 1023;
#pragma unroll
  for (int p = 0; p < 4; ++p) {
    int row = (tid >> 3) + p * 32;
    int ch = (tid & 7) * 8;
    uint4 q = *(uint4*)&Lt[row][ch];
    *(uint4*)&WhT[((long)b * DD + n0 + row) * NN + il + ch] = q;
  }
}

// -------- K5: out = elu( U @ WhT^T ), BM=64 BN=64, register prefetch --------
__global__ __launch_bounds__(256) void k_av(const ushort* __restrict__ U,
                                            const ushort* __restrict__ WhT,
                                            float* __restrict__ out) {
  __shared__ uint4 AswQ[64 * 8];
  __shared__ uint4 BswQ[64 * 8];
  int b = blockIdx.z;
  int i0 = blockIdx.y * 64;
  int n0 = blockIdx.x * 64;
  const ushort* Sb = U + (long)b * NN * NN;
  const ushort* Bb = WhT + (long)b * DD * NN;
  int tid = threadIdx.x;
  int r = tid >> 3, cs = tid & 7;
  int lane = tid & 63, wid = tid >> 6;
  int lr = lane & 15, g = lane >> 4;
  f32x4 acc[4] = {};
  uint4 a_pf[2], b_pf[2];
#pragma unroll
  for (int p = 0; p < 2; ++p) {
    int row = p * 32 + r;
    a_pf[p] = *(const uint4*)(Sb + (long)(i0 + row) * NN + cs * 8);
    b_pf[p] = *(const uint4*)(Bb + (long)(n0 + row) * NN + cs * 8);
  }
  for (int k0 = 0; k0 < NN; k0 += 64) {
#pragma unroll
    for (int p = 0; p < 2; ++p) {
      int row = p * 32 + r;
      AswQ[row * 8 + (cs ^ (row & 7))] = a_pf[p];
      BswQ[row * 8 + (cs ^ (row & 7))] = b_pf[p];
    }
    __syncthreads();
    if (k0 + 64 < NN) {
#pragma unroll
      for (int p = 0; p < 2; ++p) {
        int row = p * 32 + r;
        a_pf[p] = *(const uint4*)(Sb + (long)(i0 + row) * NN + k0 + 64 + cs * 8);
        b_pf[p] = *(const uint4*)(Bb + (long)(n0 + row) * NN + k0 + 64 + cs * 8);
      }
    }
#pragma unroll
    for (int ks = 0; ks < 2; ++ks) {
      short8v af, bfr[4];
      int slot = ks * 4 + g;
      {
        int row = wid * 16 + lr;
        af = *reinterpret_cast<const short8v*>(&AswQ[row * 8 + (slot ^ (row & 7))]);
      }
#pragma unroll
      for (int ni = 0; ni < 4; ++ni) {
        int row = ni * 16 + lr;
        bfr[ni] = *reinterpret_cast<const short8v*>(&BswQ[row * 8 + (slot ^ (row & 7))]);
      }
#pragma unroll
      for (int ni = 0; ni < 4; ++ni)
        acc[ni] = __builtin_amdgcn_mfma_f32_16x16x32_bf16(af, bfr[ni], acc[ni], 0, 0, 0);
    }
    __syncthreads();
  }
#pragma unroll
  for (int ni = 0; ni < 4; ++ni)
#pragma unroll
    for (int q = 0; q < 4; ++q) {
      int row = i0 + wid * 16 + g * 4 + q;
      int col = n0 + ni * 16 + lr;
      float x = acc[ni][q];
      x = x > 0.f ? x : expm1f(x);
      out[((long)b * NN + row) * DD + col] = x;
    }
}

extern "C" void kernel_launch(void* const* d_in, const int* in_sizes, int n_in,
                              void* d_out, int out_size, void* d_ws, size_t ws_size,
                              hipStream_t stream) {
  const float* h0 = (const float*)d_in[0];
  const float* h1 = (const float*)d_in[1];
  const int* madj = (const int*)d_in[2];
  const int* adj = (const int*)d_in[3];
  const float* W = (const float*)d_in[4];
  const float* a = (const float*)d_in[5];
  const float* A_rel = (const float*)d_in[6];
  float* out = (float*)d_out;

  float* ws = (float*)d_ws;
  float* s0 = ws;                           // 8192
  float* s1 = s0 + BN;
  float* r0 = s1 + BN;                      // 98304
  float* r1 = r0 + RR * BN;
  float* lsum = r1 + RR * BN;               // 8192
  float* Vt = lsum + BN;                    // 6656
  ushort* WTb = (ushort*)(Vt + 26 * DD);    // 65,536 ushort
  ushort* WhT = WTb + DD * DD;              // 2,097,152 ushort
  ushort* Uh = WhT + (size_t)BB * DD * NN;  // 8,388,608 ushort (bf16)

  k_prep<<<225, 256, 0, stream>>>(W, a, A_rel, WTb, Vt, lsum);
  k_proj<<<(2 * BN) / 4, 256, 0, stream>>>(h0, h1, Vt, s0, s1, r0, r1);
  k_scores<<<dim3(BB, CCH), 256, 0, stream>>>(madj, adj, s0, s1, r0, r1, Uh, lsum);
  k_mm_wh1<<<dim3(2, BN / 64), 256, 0, stream>>>(h1, WTb, lsum, WhT);
  k_av<<<dim3(DD / 64, NN / 64, BB), 256, 0, stream>>>(Uh, WhT, out);
}

// Round 16
// 167.899 us; speedup vs baseline: 2.1321x; 1.0105x over previous
//
#include <hip/hip_runtime.h>
#include <hip/hip_bf16.h>
#include <hip/hip_fp16.h>

#define BB 8
#define NN 1024
#define DD 256
#define RR 12
#define BN (BB * NN)  // 8192
#define ICH 8
#define CCH (NN / ICH)  // 128

typedef __attribute__((ext_vector_type(8))) short short8v;
typedef __attribute__((ext_vector_type(4))) float f32x4;
typedef __attribute__((ext_vector_type(4))) int int4v;
typedef __attribute__((ext_vector_type(2))) uint uint2v;

static __device__ __forceinline__ ushort f2bf(float f) {
  union { float f; uint u; } v; v.f = f;
  uint r = v.u + 0x7FFF + ((v.u >> 16) & 1);
  return (ushort)(r >> 16);
}
static __device__ __forceinline__ uint pack2(float a, float b) {
  return (uint)f2bf(a) | ((uint)f2bf(b) << 16);
}
static __device__ __forceinline__ float bfround(float f) {
  union { uint u; float f; } v; v.u = (uint)f2bf(f) << 16;
  return v.f;
}

// ---- K1: prepW transpose (blk 0..15) + Vt (16..223, parallel) + lsum (224) --
__global__ __launch_bounds__(256) void k_prep(const float* __restrict__ W,
                                              const float* __restrict__ a,
                                              const float* __restrict__ A_rel,
                                              ushort* __restrict__ WTb,
                                              float* __restrict__ Vt,
                                              float* __restrict__ lsum) {
  __shared__ float Ls[64][65];
  int blk = blockIdx.x, tid = threadIdx.x;
  if (blk < 16) {
    int k0 = (blk & 3) * 64, d0 = (blk >> 2) * 64;
    int rr = tid >> 4, c = (tid & 15) * 4;
#pragma unroll
    for (int p = 0; p < 4; ++p) {
      int row = p * 16 + rr;
      float4 v = *(const float4*)&W[(k0 + row) * DD + d0 + c];
      Ls[row][c] = v.x; Ls[row][c + 1] = v.y; Ls[row][c + 2] = v.z; Ls[row][c + 3] = v.w;
    }
    __syncthreads();
    int r2 = tid >> 3, cc = (tid & 7) * 8;
#pragma unroll
    for (int p = 0; p < 2; ++p) {
      int d = p * 32 + r2;
      uint4 q;
      q.x = pack2(Ls[cc + 0][d], Ls[cc + 1][d]);
      q.y = pack2(Ls[cc + 2][d], Ls[cc + 3][d]);
      q.z = pack2(Ls[cc + 4][d], Ls[cc + 5][d]);
      q.w = pack2(Ls[cc + 6][d], Ls[cc + 7][d]);
      *(uint4*)&WTb[(d0 + d) * DD + k0 + cc] = q;
    }
  } else if (blk == 224) {
    float4 z = make_float4(0.f, 0.f, 0.f, 0.f);
#pragma unroll
    for (int p = 0; p < 8; ++p)
      *(float4*)&lsum[(p * 256 + tid) * 4] = z;
  } else {
    int idx = blk - 16;            // 0..207
    int combo = idx >> 3;          // 0..25
    int sub = idx & 7;             // 0..7 (32 k's each)
    int half = combo >= 13 ? 1 : 0;
    int c = combo - half * 13;
    int lane = tid & 63, w = tid >> 6;
    const float* X = (c == 0) ? &a[half * DD] : &A_rel[(c - 1) * 2 * DD + half * DD];
    float4 x4 = *(const float4*)&X[lane * 4];
#pragma unroll
    for (int kk = 0; kk < 8; ++kk) {
      int k = sub * 32 + kk * 4 + w;
      float4 w4 = *(const float4*)&W[k * DD + lane * 4];
      float p = w4.x * x4.x + w4.y * x4.y + w4.z * x4.z + w4.w * x4.w;
#pragma unroll
      for (int off = 32; off; off >>= 1) p += __shfl_xor(p, off);
      if (lane == 0) Vt[(half * 13 + c) * DD + k] = p;
    }
  }
}

// ---------------- K2: per-node projections from h and Vt ----------------
__global__ __launch_bounds__(256) void k_proj(const float* __restrict__ h0,
                                              const float* __restrict__ h1,
                                              const float* __restrict__ Vt,
                                              float* __restrict__ s0, float* __restrict__ s1,
                                              float* __restrict__ r0, float* __restrict__ r1) {
  int wid = (blockIdx.x * 256 + threadIdx.x) >> 6;  // 0..16383
  int lane = threadIdx.x & 63;
  int mat = wid >> 13;
  int row = wid & (BN - 1);
  const float* h = mat ? h1 : h0;
  float4 h4 = *(const float4*)&h[(long)row * DD + lane * 4];
  float p[13];
#pragma unroll
  for (int c = 0; c < 13; ++c) {
    float4 v4 = *(const float4*)&Vt[(mat * 13 + c) * DD + lane * 4];
    p[c] = h4.x * v4.x + h4.y * v4.y + h4.z * v4.z + h4.w * v4.w;
  }
#pragma unroll
  for (int off = 32; off; off >>= 1)
#pragma unroll
    for (int c = 0; c < 13; ++c) p[c] += __shfl_xor(p[c], off);
  if (lane == 0) {
    if (mat == 0) {
      s0[row] = p[0];
      for (int c = 1; c < 13; ++c) r0[(c - 1) * BN + row] = p[c];
    } else {
      s1[row] = p[0];
      for (int c = 1; c < 13; ++c) r1[(c - 1) * BN + row] = p[c];
    }
  }
}

// ------ K3: scores (exact R13: unroll 2, NT loads, grid (BB,CCH)) -----------
__global__ __launch_bounds__(256) void k_scores(const int* __restrict__ madj,
                                                const int* __restrict__ adj,
                                                const float* __restrict__ s0,
                                                const float* __restrict__ s1,
                                                const float* __restrict__ r0,
                                                const float* __restrict__ r1,
                                                ushort* __restrict__ U,
                                                float* __restrict__ lsum) {
  int b = blockIdx.x, c = blockIdx.y;
  int tid = threadIdx.x;
  int j4 = tid * 4;
  int i0 = c * ICH;
  __shared__ float s0c[ICH];
  __shared__ float r0c[RR][ICH];
  if (tid < (RR + 1) * ICH) {
    int v = tid / ICH, i = tid % ICH;
    float x = (v == 0) ? s0[b * NN + i0 + i] : r0[(v - 1) * BN + b * NN + i0 + i];
    if (v == 0) s0c[i] = x; else r0c[v - 1][i] = x;
  }
  __syncthreads();
  float4 s14 = *(const float4*)&s1[b * NN + j4];
  float rel[ICH][4] = {};
#pragma unroll 2
  for (int r = 0; r < RR; ++r) {
    float4 r1v = *(const float4*)&r1[r * BN + b * NN + j4];
#pragma unroll
    for (int i = 0; i < ICH; ++i) {
      int4v mv = __builtin_nontemporal_load(
          (const int4v*)&madj[(((long)r * BB + b) * NN + i0 + i) * NN + j4]);
      float r0v = r0c[r][i];
      float t0 = r0v + r1v.x; t0 = t0 >= 0.f ? t0 : 0.2f * t0;
      float t1 = r0v + r1v.y; t1 = t1 >= 0.f ? t1 : 0.2f * t1;
      float t2 = r0v + r1v.z; t2 = t2 >= 0.f ? t2 : 0.2f * t2;
      float t3 = r0v + r1v.w; t3 = t3 >= 0.f ? t3 : 0.2f * t3;
      if (mv.x > 0) rel[i][0] += t0;
      if (mv.y > 0) rel[i][1] += t1;
      if (mv.z > 0) rel[i][2] += t2;
      if (mv.w > 0) rel[i][3] += t3;
    }
  }
  float l0 = 0.f, l1 = 0.f, l2 = 0.f, l3 = 0.f;
#pragma unroll
  for (int i = 0; i < ICH; ++i) {
    int4v av = __builtin_nontemporal_load(
        (const int4v*)&adj[((long)b * NN + i0 + i) * NN + j4]);
    float s0v = s0c[i];
    float u0, u1, u2, u3;
    { float e = s0v + s14.x; e = e >= 0.f ? e : 0.2f * e;
      u0 = __expf((av.x > 0 ? e : -9e15f) + 0.01f * rel[i][0] - 4.0f); }
    { float e = s0v + s14.y; e = e >= 0.f ? e : 0.2f * e;
      u1 = __expf((av.y > 0 ? e : -9e15f) + 0.01f * rel[i][1] - 4.0f); }
    { float e = s0v + s14.z; e = e >= 0.f ? e : 0.2f * e;
      u2 = __expf((av.z > 0 ? e : -9e15f) + 0.01f * rel[i][2] - 4.0f); }
    { float e = s0v + s14.w; e = e >= 0.f ? e : 0.2f * e;
      u3 = __expf((av.w > 0 ? e : -9e15f) + 0.01f * rel[i][3] - 4.0f); }
    u0 = bfround(u0); u1 = bfround(u1); u2 = bfround(u2); u3 = bfround(u3);
    uint2v so;
    so.x = pack2(u0, u1);
    so.y = pack2(u2, u3);
    *(uint2v*)&U[((long)b * NN + i0 + i) * NN + j4] = so;
    l0 += u0; l1 += u1; l2 += u2; l3 += u3;
  }
  float* lp = &lsum[b * NN + j4];
  atomicAdd(lp + 0, l0);
  atomicAdd(lp + 1, l1);
  atomicAdd(lp + 2, l2);
  atomicAdd(lp + 3, l3);
}

// ------ K4: WhT[b][d][i] = bf16( (h1@W)[i][d] / lsum[i] ), fused transpose --
__global__ __launch_bounds__(256) void k_mm_wh1(const float* __restrict__ h1,
                                                const ushort* __restrict__ WTb,
                                                const float* __restrict__ lsum,
                                                ushort* __restrict__ WhT) {
  __shared__ __align__(16) char smraw[24576];
  uint4* AswQ = (uint4*)smraw;
  uint4* BswQ = (uint4*)(smraw + 8192);
  typedef ushort LtRow[72];
  LtRow* Lt = (LtRow*)smraw;
  int n0 = blockIdx.x * 128, i0 = blockIdx.y * 64;
  int tid = threadIdx.x;
  int r = tid >> 3, cs = tid & 7;
  int lane = tid & 63, wid = tid >> 6;
  int wm = wid >> 1, wn = wid & 1;
  int lr = lane & 15, g = lane >> 4;
  f32x4 acc[2][4] = {};
  for (int k0 = 0; k0 < DD; k0 += 64) {
#pragma unroll
    for (int p = 0; p < 2; ++p) {
      int row = p * 32 + r;
      const float* src = h1 + (long)(i0 + row) * DD + k0 + cs * 8;
      float4 v0 = *(const float4*)src;
      float4 v1 = *(const float4*)(src + 4);
      uint4 q;
      q.x = pack2(v0.x, v0.y); q.y = pack2(v0.z, v0.w);
      q.z = pack2(v1.x, v1.y); q.w = pack2(v1.z, v1.w);
      AswQ[row * 8 + (cs ^ (row & 7))] = q;
    }
#pragma unroll
    for (int p = 0; p < 4; ++p) {
      int row = p * 32 + r;
      uint4 q = *(const uint4*)(WTb + (long)(n0 + row) * DD + k0 + cs * 8);
      BswQ[row * 8 + (cs ^ (row & 7))] = q;
    }
    __syncthreads();
#pragma unroll
    for (int ks = 0; ks < 2; ++ks) {
      short8v af[2], bfr[4];
      int slot = ks * 4 + g;
#pragma unroll
      for (int mi = 0; mi < 2; ++mi) {
        int row = wm * 32 + mi * 16 + lr;
        af[mi] = *reinterpret_cast<const short8v*>(&AswQ[row * 8 + (slot ^ (row & 7))]);
      }
#pragma unroll
      for (int ni = 0; ni < 4; ++ni) {
        int row = wn * 64 + ni * 16 + lr;
        bfr[ni] = *reinterpret_cast<const short8v*>(&BswQ[row * 8 + (slot ^ (row & 7))]);
      }
#pragma unroll
      for (int mi = 0; mi < 2; ++mi)
#pragma unroll
        for (int ni = 0; ni < 4; ++ni)
          acc[mi][ni] = __builtin_amdgcn_mfma_f32_16x16x32_bf16(af[mi], bfr[ni], acc[mi][ni], 0, 0, 0);
    }
    __syncthreads();
  }
#pragma unroll
  for (int mi = 0; mi < 2; ++mi) {
    int ib = wm * 32 + mi * 16 + g * 4;
    float4 lv = *(const float4*)&lsum[i0 + ib];
    float inv0 = 1.0f / lv.x, inv1 = 1.0f / lv.y, inv2 = 1.0f / lv.z, inv3 = 1.0f / lv.w;
#pragma unroll
    for (int ni = 0; ni < 4; ++ni) {
      int d = wn * 64 + ni * 16 + lr;
      uint2 w;
      w.x = pack2(acc[mi][ni][0] * inv0, acc[mi][ni][1] * inv1);
      w.y = pack2(acc[mi][ni][2] * inv2, acc[mi][ni][3] * inv3);
      *(uint2*)&Lt[d][ib] = w;
    }
  }
  __syncthreads();
  int b = i0 >> 10, il = i0 & 1023;
#pragma unroll
  for (int p = 0; p < 4; ++p) {
    int row = (tid >> 3) + p * 32;
    int ch = (tid & 7) * 8;
    uint4 q = *(uint4*)&Lt[row][ch];
    *(uint4*)&WhT[((long)b * DD + n0 + row) * NN + il + ch] = q;
  }
}

// -------- K5: out = elu( U @ WhT^T ), BM=64 BN=64, prefetch + XCD swizzle ---
// Bijective remap (512 = 8*64): XCD k executes all tiles of batch b=k, so
// each U A-panel's 4 col-tile readers and the 512KB WhT_b share one L2.
__global__ __launch_bounds__(256) void k_av(const ushort* __restrict__ U,
                                            const ushort* __restrict__ WhT,
                                            float* __restrict__ out) {
  __shared__ uint4 AswQ[64 * 8];
  __shared__ uint4 BswQ[64 * 8];
  int bid = blockIdx.x + 4 * (blockIdx.y + 16 * blockIdx.z);  // 0..511
  int nb = (bid & 7) * 64 + (bid >> 3);                       // XCD-contiguous
  int b = nb >> 6;
  int i0 = ((nb >> 2) & 15) * 64;
  int n0 = (nb & 3) * 64;
  const ushort* Sb = U + (long)b * NN * NN;
  const ushort* Bb = WhT + (long)b * DD * NN;
  int tid = threadIdx.x;
  int r = tid >> 3, cs = tid & 7;
  int lane = tid & 63, wid = tid >> 6;
  int lr = lane & 15, g = lane >> 4;
  f32x4 acc[4] = {};
  uint4 a_pf[2], b_pf[2];
#pragma unroll
  for (int p = 0; p < 2; ++p) {
    int row = p * 32 + r;
    a_pf[p] = *(const uint4*)(Sb + (long)(i0 + row) * NN + cs * 8);
    b_pf[p] = *(const uint4*)(Bb + (long)(n0 + row) * NN + cs * 8);
  }
  for (int k0 = 0; k0 < NN; k0 += 64) {
#pragma unroll
    for (int p = 0; p < 2; ++p) {
      int row = p * 32 + r;
      AswQ[row * 8 + (cs ^ (row & 7))] = a_pf[p];
      BswQ[row * 8 + (cs ^ (row & 7))] = b_pf[p];
    }
    __syncthreads();
    if (k0 + 64 < NN) {
#pragma unroll
      for (int p = 0; p < 2; ++p) {
        int row = p * 32 + r;
        a_pf[p] = *(const uint4*)(Sb + (long)(i0 + row) * NN + k0 + 64 + cs * 8);
        b_pf[p] = *(const uint4*)(Bb + (long)(n0 + row) * NN + k0 + 64 + cs * 8);
      }
    }
#pragma unroll
    for (int ks = 0; ks < 2; ++ks) {
      short8v af, bfr[4];
      int slot = ks * 4 + g;
      {
        int row = wid * 16 + lr;
        af = *reinterpret_cast<const short8v*>(&AswQ[row * 8 + (slot ^ (row & 7))]);
      }
#pragma unroll
      for (int ni = 0; ni < 4; ++ni) {
        int row = ni * 16 + lr;
        bfr[ni] = *reinterpret_cast<const short8v*>(&BswQ[row * 8 + (slot ^ (row & 7))]);
      }
#pragma unroll
      for (int ni = 0; ni < 4; ++ni)
        acc[ni] = __builtin_amdgcn_mfma_f32_16x16x32_bf16(af, bfr[ni], acc[ni], 0, 0, 0);
    }
    __syncthreads();
  }
#pragma unroll
  for (int ni = 0; ni < 4; ++ni)
#pragma unroll
    for (int q = 0; q < 4; ++q) {
      int row = i0 + wid * 16 + g * 4 + q;
      int col = n0 + ni * 16 + lr;
      float x = acc[ni][q];
      x = x > 0.f ? x : expm1f(x);
      out[((long)b * NN + row) * DD + col] = x;
    }
}

extern "C" void kernel_launch(void* const* d_in, const int* in_sizes, int n_in,
                              void* d_out, int out_size, void* d_ws, size_t ws_size,
                              hipStream_t stream) {
  const float* h0 = (const float*)d_in[0];
  const float* h1 = (const float*)d_in[1];
  const int* madj = (const int*)d_in[2];
  const int* adj = (const int*)d_in[3];
  const float* W = (const float*)d_in[4];
  const float* a = (const float*)d_in[5];
  const float* A_rel = (const float*)d_in[6];
  float* out = (float*)d_out;

  float* ws = (float*)d_ws;
  float* s0 = ws;                           // 8192
  float* s1 = s0 + BN;
  float* r0 = s1 + BN;                      // 98304
  float* r1 = r0 + RR * BN;
  float* lsum = r1 + RR * BN;               // 8192
  float* Vt = lsum + BN;                    // 6656
  ushort* WTb = (ushort*)(Vt + 26 * DD);    // 65,536 ushort
  ushort* WhT = WTb + DD * DD;              // 2,097,152 ushort
  ushort* Uh = WhT + (size_t)BB * DD * NN;  // 8,388,608 ushort (bf16)

  k_prep<<<225, 256, 0, stream>>>(W, a, A_rel, WTb, Vt, lsum);
  k_proj<<<(2 * BN) / 4, 256, 0, stream>>>(h0, h1, Vt, s0, s1, r0, r1);
  k_scores<<<dim3(BB, CCH), 256, 0, stream>>>(madj, adj, s0, s1, r0, r1, Uh, lsum);
  k_mm_wh1<<<dim3(2, BN / 64), 256, 0, stream>>>(h1, WTb, lsum, WhT);
  k_av<<<dim3(DD / 64, NN / 64, BB), 256, 0, stream>>>(Uh, WhT, out);
}